// Round 10
// baseline (966.946 us; speedup 1.0000x reference)
//
#include <hip/hip_runtime.h>
#include <hip/hip_bf16.h>

#define BB 1024
#define DD 512
#define KK 1024
#define HH 32

typedef float f32x2 __attribute__((ext_vector_type(2)));
typedef float f32x4 __attribute__((ext_vector_type(4)));

// d_out (f32): [0,1048576) logits; [1048576,1049600) bmu_index; [1049600] delta
// ws: amin 1024xu64 @0 (8KB); partials 1024xf32 @8192 (4KB); rowstats @12288 (8KB)

__device__ __forceinline__ float dev_invtemp(int traw) {
    int t = traw;
    if (t > 100 || t < 0) t = (int)__int_as_float(traw);
    const float tf = (float)t;
    float temp;
    if (10.0f > tf)
        temp = 1e-8f + 0.5f * (10.0f - 1e-8f) * (1.0f + cosf(tf * 0.31415926535897932f));
    else
        temp = 1e-8f;
    return 1.0f / temp;
}

// ---- VOP3P packed f32 (gfx950: only pk_add/pk_mul/pk_fma exist for f32) ----
__device__ __forceinline__ f32x2 pk_sub(f32x2 a, f32x2 b) {   // {a.x-b.x, a.y-b.y}
    f32x2 r;
    asm("v_pk_add_f32 %0, %1, %2 neg_lo:[0,1] neg_hi:[0,1]" : "=v"(r) : "v"(a), "v"(b));
    return r;
}
__device__ __forceinline__ f32x2 pk_sq_acc(f32x2 d, f32x2 acc) {
    // acc + d*d with SEPARATE roundings (mul then add) — numpy-exact, NOT fma
    f32x2 m, r;
    asm("v_pk_mul_f32 %0, %1, %1" : "=v"(m) : "v"(d));
    asm("v_pk_add_f32 %0, %1, %2" : "=v"(r) : "v"(m), "v"(acc));
    return r;
}

// ---------------------------------------------------------------------------
// Kernel 1: per-row MLP; logits -> d_out (f32); softmax stats -> rowstats.
// ---------------------------------------------------------------------------
__global__ __launch_bounds__(256) void mlp_softmax_kernel(
    const float* __restrict__ X, const float* __restrict__ W1,
    const float* __restrict__ B1, const float* __restrict__ W2,
    const float* __restrict__ B2, const float* __restrict__ G,
    const int* __restrict__ T, float* __restrict__ out_logits,
    float2* __restrict__ rowstats, unsigned long long* __restrict__ amin)
{
    const int b = blockIdx.x;
    const int tid = threadIdx.x;
    __shared__ float xs[DD];
    __shared__ float hp[8][HH];
    __shared__ float hs[HH];
    __shared__ float red[256];

    if (tid < 128) ((float4*)xs)[tid] = ((const float4*)(X + (size_t)b * DD))[tid];
    if (tid == 0) amin[b] = ~0ULL;
    __syncthreads();

    {
        const int h = tid & 31, seg = tid >> 5;
        const float* w1p = W1 + (seg * 64) * HH + h;
        const float* xp = xs + seg * 64;
        float p = 0.f;
        #pragma unroll 8
        for (int d = 0; d < 64; ++d) p = fmaf(xp[d], w1p[d * HH], p);
        hp[seg][h] = p;
    }
    __syncthreads();
    if (tid < HH) {
        float a = ((hp[0][tid] + hp[1][tid]) + (hp[2][tid] + hp[3][tid]))
                + ((hp[4][tid] + hp[5][tid]) + (hp[6][tid] + hp[7][tid]));
        a += B1[tid];
        hs[tid] = a > 0.f ? a : 0.f;
    }
    const float invt = dev_invtemp(*T);
    __syncthreads();

    float sv[4];
    #pragma unroll
    for (int j = 0; j < 4; ++j) {
        const int k = tid + j * 256;
        float acc = B2[k];
        #pragma unroll
        for (int h = 0; h < HH; ++h) acc = fmaf(hs[h], W2[h * KK + k], acc);
        out_logits[(size_t)b * KK + k] = acc;
        sv[j] = (acc + G[(size_t)b * KK + k]) * invt;
    }

    float m = fmaxf(fmaxf(sv[0], sv[1]), fmaxf(sv[2], sv[3]));
    red[tid] = m;
    __syncthreads();
    for (int st = 128; st > 0; st >>= 1) {
        if (tid < st) red[tid] = fmaxf(red[tid], red[tid + st]);
        __syncthreads();
    }
    const float mx = red[0];
    __syncthreads();

    float psum = 0.f;
    #pragma unroll
    for (int j = 0; j < 4; ++j) psum += expf(sv[j] - mx);
    red[tid] = psum;
    __syncthreads();
    for (int st = 128; st > 0; st >>= 1) {
        if (tid < st) red[tid] += red[tid + st];
        __syncthreads();
    }
    if (tid == 0) rowstats[b] = make_float2(mx, 1.0f / red[0]);
}

// ---------------------------------------------------------------------------
// Kernel 2 v7: round-8 structure (32b x 32k tile, d-packed VOP3P, C k-major in
// double-buffered LDS, X direct from global) with:
//  - __launch_bounds__(256,6): cap VGPR for 6 waves/SIMD (r8 was 120 -> 4)
//  - no X group-prefetch regs (r6 proved useless; frees VGPR)
//  - bijective XCD swizzle of flattened blockIdx (1024%8==0): each XCD's L2
//    holds 4 b-panels + C (~2.25MB < 4MB) -> preserves r8's 13.4MB fetch.
// np-exact pairwise preserved (packed accum a holds np accums {2a,2a+1}).
// ---------------------------------------------------------------------------
__global__ __launch_bounds__(256, 6) void dist_kernel(
    const float* __restrict__ X, const float* __restrict__ C,
    const float* __restrict__ L, const float* __restrict__ G,
    const float2* __restrict__ RS, const int* __restrict__ T,
    unsigned long long* __restrict__ amin, float* __restrict__ partials)
{
    #pragma clang fp contract(off)
    __shared__ float cs[2][32][36];
    __shared__ float red[256];
    __shared__ unsigned long long am[32][16];

    const int tid = threadIdx.x;
    const int tx = tid & 15, ty = tid >> 4;      // tx: k-slot, ty: b-pair
    // XCD-aware bijective swizzle: nwg=1024, 128 per XCD chunk
    const int wg = (blockIdx.x & 7) * 128 + (blockIdx.x >> 3);
    const int bx = wg & 31, by = wg >> 5;
    const int k0 = bx * 32, b0 = by * 32;
    const int r = tid >> 3;                       // 0..31 c-row (k) to stage
    const int q = (tid & 7) * 4;                  // 0..28 d-offset in chunk

    const float* cg = C + (size_t)(k0 + r) * DD + q;
    const float* xr0 = X + (size_t)(b0 + 2 * ty) * DD;
    const float* xr1 = xr0 + DD;

    const f32x2 zero2 = {0.f, 0.f};
    float l1[2][2] = {{0.f, 0.f}, {0.f, 0.f}};    // [k-slot][b]
    f32x2 rc[2][2][4];                            // [k][b][packed np accum]
    float s01[2][2], s23[2][2];
    #pragma unroll
    for (int kk = 0; kk < 2; ++kk)
        #pragma unroll
        for (int bb = 0; bb < 2; ++bb) {
            s01[kk][bb] = 0.f; s23[kk][bb] = 0.f;
            #pragma unroll
            for (int a = 0; a < 4; ++a) rc[kk][bb][a] = zero2;
        }

    f32x4 cv = *(const f32x4*)cg;                 // chunk 0 C stage

    #pragma unroll 1
    for (int t = 0; t < 16; ++t) {
        const int buf = t & 1;
        *(f32x4*)&cs[buf][r][q] = cv;
        if (t < 15) cv = *(const f32x4*)(cg + (t + 1) * 32);  // reg-only: barrier-safe
        __syncthreads();

        const int d0 = t * 32;
        #pragma unroll
        for (int g = 0; g < 8; ++g) {
            const f32x4 xq0 = *(const f32x4*)(xr0 + d0 + 4 * g);
            const f32x4 xq1 = *(const f32x4*)(xr1 + d0 + 4 * g);
            const f32x2 c0a = *(const f32x2*)&cs[buf][tx][4 * g];
            const f32x2 c0b = *(const f32x2*)&cs[buf][tx][4 * g + 2];
            const f32x2 c1a = *(const f32x2*)&cs[buf][tx + 16][4 * g];
            const f32x2 c1b = *(const f32x2*)&cs[buf][tx + 16][4 * g + 2];
            const f32x2 x0a = __builtin_shufflevector(xq0, xq0, 0, 1);
            const f32x2 x0b = __builtin_shufflevector(xq0, xq0, 2, 3);
            const f32x2 x1a = __builtin_shufflevector(xq1, xq1, 0, 1);
            const f32x2 x1b = __builtin_shufflevector(xq1, xq1, 2, 3);
            const int a0 = (2 * g) & 3;   // compile-time after unroll
            const int a1 = a0 + 1;

            {   // d-pair (4g, 4g+1) -> packed accum a0
                f32x2 d00 = pk_sub(c0a, x0a);
                rc[0][0][a0] = pk_sq_acc(d00, rc[0][0][a0]);
                l1[0][0] += fabsf(d00.x); l1[0][0] += fabsf(d00.y);
                f32x2 d01 = pk_sub(c0a, x1a);
                rc[0][1][a0] = pk_sq_acc(d01, rc[0][1][a0]);
                l1[0][1] += fabsf(d01.x); l1[0][1] += fabsf(d01.y);
                f32x2 d10 = pk_sub(c1a, x0a);
                rc[1][0][a0] = pk_sq_acc(d10, rc[1][0][a0]);
                l1[1][0] += fabsf(d10.x); l1[1][0] += fabsf(d10.y);
                f32x2 d11 = pk_sub(c1a, x1a);
                rc[1][1][a0] = pk_sq_acc(d11, rc[1][1][a0]);
                l1[1][1] += fabsf(d11.x); l1[1][1] += fabsf(d11.y);
            }
            {   // d-pair (4g+2, 4g+3) -> packed accum a1
                f32x2 d00 = pk_sub(c0b, x0b);
                rc[0][0][a1] = pk_sq_acc(d00, rc[0][0][a1]);
                l1[0][0] += fabsf(d00.x); l1[0][0] += fabsf(d00.y);
                f32x2 d01 = pk_sub(c0b, x1b);
                rc[0][1][a1] = pk_sq_acc(d01, rc[0][1][a1]);
                l1[0][1] += fabsf(d01.x); l1[0][1] += fabsf(d01.y);
                f32x2 d10 = pk_sub(c1b, x0b);
                rc[1][0][a1] = pk_sq_acc(d10, rc[1][0][a1]);
                l1[1][0] += fabsf(d10.x); l1[1][0] += fabsf(d10.y);
                f32x2 d11 = pk_sub(c1b, x1b);
                rc[1][1][a1] = pk_sq_acc(d11, rc[1][1][a1]);
                l1[1][1] += fabsf(d11.x); l1[1][1] += fabsf(d11.y);
            }
        }

        if ((t & 3) == 3) {               // end of a 128-element block
            const int blk = t >> 2;       // 0..3
            #pragma unroll
            for (int kk = 0; kk < 2; ++kk)
                #pragma unroll
                for (int bb = 0; bb < 2; ++bb) {
                    // == ((r0+r1)+(r2+r3)) + ((r4+r5)+(r6+r7)) bit-exactly
                    const float b01 = (rc[kk][bb][0].x + rc[kk][bb][0].y)
                                    + (rc[kk][bb][1].x + rc[kk][bb][1].y);
                    const float b23 = (rc[kk][bb][2].x + rc[kk][bb][2].y)
                                    + (rc[kk][bb][3].x + rc[kk][bb][3].y);
                    const float bsum = b01 + b23;
                    if (blk == 0)      s01[kk][bb] = bsum;
                    else if (blk == 1) s01[kk][bb] = s01[kk][bb] + bsum;
                    else if (blk == 2) s23[kk][bb] = bsum;
                    else               s23[kk][bb] = s23[kk][bb] + bsum;
                    #pragma unroll
                    for (int a = 0; a < 4; ++a) rc[kk][bb][a] = zero2;
                }
        }
    }

    // ---- z recompute + delta partial + per-thread argmin pack ----
    const float invt = dev_invtemp(*T);
    float zp = 0.f;
    #pragma unroll
    for (int i = 0; i < 2; ++i) {
        const int b = b0 + 2 * ty + i;
        const float2 rs = RS[b];
        const int ka = k0 + tx;          // k-slot 0
        const int kb = k0 + tx + 16;     // k-slot 1
        const float fd0 = s01[0][i] + s23[0][i];   // ((B0+B1)+(B2+B3))
        const float fd1 = s01[1][i] + s23[1][i];
        const float z0 = expf((L[(size_t)b * KK + ka] + G[(size_t)b * KK + ka]) * invt - rs.x) * rs.y;
        const float z1 = expf((L[(size_t)b * KK + kb] + G[(size_t)b * KK + kb]) * invt - rs.x) * rs.y;
        zp += l1[0][i] * z0 + l1[1][i] * z1;
        const unsigned long long p0 =
            ((unsigned long long)__float_as_uint(fd0) << 32) | (unsigned long long)ka;
        const unsigned long long p1 =
            ((unsigned long long)__float_as_uint(fd1) << 32) | (unsigned long long)kb;
        am[2 * ty + i][tx] = p0 < p1 ? p0 : p1;
    }

    red[tid] = zp;
    __syncthreads();
    for (int st = 128; st > 0; st >>= 1) {
        if (tid < st) red[tid] += red[tid + st];
        __syncthreads();
    }
    if (tid == 0) partials[wg] = red[0];

    if (tid < 32) {
        unsigned long long mv = am[tid][0];
        #pragma unroll
        for (int c = 1; c < 16; ++c) {
            unsigned long long v = am[tid][c];
            mv = v < mv ? v : mv;
        }
        atomicMin(&amin[b0 + tid], mv);
    }
}

// ---------------------------------------------------------------------------
// Kernel 3: finalize.
// ---------------------------------------------------------------------------
__global__ __launch_bounds__(1024) void finalize_kernel(
    const unsigned long long* __restrict__ amin,
    const float* __restrict__ partials, float* __restrict__ out)
{
    const int t = threadIdx.x;
    __shared__ float red[1024];
    const unsigned int idx = (unsigned int)(amin[t] & 0xFFFFFFFFULL);
    out[1048576 + t] = (float)idx;
    red[t] = partials[t];
    __syncthreads();
    for (int st = 512; st > 0; st >>= 1) {
        if (t < st) red[t] += red[t + st];
        __syncthreads();
    }
    if (t == 0)
        out[1049600] = red[0] * (1.0f / 536870912.0f); // /(B*K*D)
}

extern "C" void kernel_launch(void* const* d_in, const int* in_sizes, int n_in,
                              void* d_out, int out_size, void* d_ws, size_t ws_size,
                              hipStream_t stream) {
    const float* X  = (const float*)d_in[0];
    const float* C  = (const float*)d_in[1];
    const float* W1 = (const float*)d_in[2];
    const float* B1 = (const float*)d_in[3];
    const float* W2 = (const float*)d_in[4];
    const float* B2 = (const float*)d_in[5];
    const float* G  = (const float*)d_in[6];
    const int*   T  = (const int*)d_in[7];
    float* out = (float*)d_out;

    char* ws = (char*)d_ws;
    unsigned long long* amin = (unsigned long long*)ws;          // 8 KB
    float* partials = (float*)(ws + 8192);                       // 4 KB
    float2* rowstats = (float2*)(ws + 12288);                    // 8 KB

    mlp_softmax_kernel<<<BB, 256, 0, stream>>>(X, W1, B1, W2, B2, G, T, out, rowstats, amin);
    dist_kernel<<<1024, 256, 0, stream>>>(X, C, out, G, rowstats, T, amin, partials);
    finalize_kernel<<<1, 1024, 0, stream>>>(amin, partials, out);
}

// Round 11
// 81.640 us; speedup vs baseline: 11.8440x; 11.8440x over previous
//
#include <hip/hip_runtime.h>
#include <hip/hip_bf16.h>

#define BB 1024
#define DD 512
#define KK 1024
#define HH 32

typedef float f32x2 __attribute__((ext_vector_type(2)));
typedef float f32x4 __attribute__((ext_vector_type(4)));

// d_out (f32): [0,1048576) logits; [1048576,1049600) bmu_index; [1049600] delta
// ws: amin 1024xu64 @0 (8KB); partials 1024xf32 @8192 (4KB); rowstats @12288 (8KB)

__device__ __forceinline__ float dev_invtemp(int traw) {
    int t = traw;
    if (t > 100 || t < 0) t = (int)__int_as_float(traw);
    const float tf = (float)t;
    float temp;
    if (10.0f > tf)
        temp = 1e-8f + 0.5f * (10.0f - 1e-8f) * (1.0f + cosf(tf * 0.31415926535897932f));
    else
        temp = 1e-8f;
    return 1.0f / temp;
}

// ---- VOP3P packed f32 (gfx950: only pk_add/pk_mul/pk_fma exist for f32) ----
__device__ __forceinline__ f32x2 pk_sub(f32x2 a, f32x2 b) {   // {a.x-b.x, a.y-b.y}
    f32x2 r;
    asm("v_pk_add_f32 %0, %1, %2 neg_lo:[0,1] neg_hi:[0,1]" : "=v"(r) : "v"(a), "v"(b));
    return r;
}
__device__ __forceinline__ f32x2 pk_sq_acc(f32x2 d, f32x2 acc) {
    // acc + d*d with SEPARATE roundings (mul then add) — numpy-exact, NOT fma
    f32x2 m, r;
    asm("v_pk_mul_f32 %0, %1, %1" : "=v"(m) : "v"(d));
    asm("v_pk_add_f32 %0, %1, %2" : "=v"(r) : "v"(m), "v"(acc));
    return r;
}
__device__ __forceinline__ f32x2 vlo(f32x4 v) { return __builtin_shufflevector(v, v, 0, 1); }
__device__ __forceinline__ f32x2 vhi(f32x4 v) { return __builtin_shufflevector(v, v, 2, 3); }

// ---------------------------------------------------------------------------
// Kernel 1: per-row MLP; logits -> d_out (f32); softmax stats -> rowstats.
// ---------------------------------------------------------------------------
__global__ __launch_bounds__(256) void mlp_softmax_kernel(
    const float* __restrict__ X, const float* __restrict__ W1,
    const float* __restrict__ B1, const float* __restrict__ W2,
    const float* __restrict__ B2, const float* __restrict__ G,
    const int* __restrict__ T, float* __restrict__ out_logits,
    float2* __restrict__ rowstats, unsigned long long* __restrict__ amin)
{
    const int b = blockIdx.x;
    const int tid = threadIdx.x;
    __shared__ float xs[DD];
    __shared__ float hp[8][HH];
    __shared__ float hs[HH];
    __shared__ float red[256];

    if (tid < 128) ((float4*)xs)[tid] = ((const float4*)(X + (size_t)b * DD))[tid];
    if (tid == 0) amin[b] = ~0ULL;
    __syncthreads();

    {
        const int h = tid & 31, seg = tid >> 5;
        const float* w1p = W1 + (seg * 64) * HH + h;
        const float* xp = xs + seg * 64;
        float p = 0.f;
        #pragma unroll 8
        for (int d = 0; d < 64; ++d) p = fmaf(xp[d], w1p[d * HH], p);
        hp[seg][h] = p;
    }
    __syncthreads();
    if (tid < HH) {
        float a = ((hp[0][tid] + hp[1][tid]) + (hp[2][tid] + hp[3][tid]))
                + ((hp[4][tid] + hp[5][tid]) + (hp[6][tid] + hp[7][tid]));
        a += B1[tid];
        hs[tid] = a > 0.f ? a : 0.f;
    }
    const float invt = dev_invtemp(*T);
    __syncthreads();

    float sv[4];
    #pragma unroll
    for (int j = 0; j < 4; ++j) {
        const int k = tid + j * 256;
        float acc = B2[k];
        #pragma unroll
        for (int h = 0; h < HH; ++h) acc = fmaf(hs[h], W2[h * KK + k], acc);
        out_logits[(size_t)b * KK + k] = acc;
        sv[j] = (acc + G[(size_t)b * KK + k]) * invt;
    }

    float m = fmaxf(fmaxf(sv[0], sv[1]), fmaxf(sv[2], sv[3]));
    red[tid] = m;
    __syncthreads();
    for (int st = 128; st > 0; st >>= 1) {
        if (tid < st) red[tid] = fmaxf(red[tid], red[tid + st]);
        __syncthreads();
    }
    const float mx = red[0];
    __syncthreads();

    float psum = 0.f;
    #pragma unroll
    for (int j = 0; j < 4; ++j) psum += expf(sv[j] - mx);
    red[tid] = psum;
    __syncthreads();
    for (int st = 128; st > 0; st >>= 1) {
        if (tid < st) red[tid] += red[tid + st];
        __syncthreads();
    }
    if (tid == 0) rowstats[b] = make_float2(mx, 1.0f / red[0]);
}

// ---------------------------------------------------------------------------
// Kernel 2 v8: r8 structure + X staged in LDS alongside C (both k-/b-major,
// double-buffered, one barrier/chunk). Inner loop: pure LDS (4x ds_read_b128
// per g) + pk math — NO global loads in the hot loop (the ~200cy L2 latency
// that was the constant ~37us idle). Staging prefetch (2 global loads/chunk)
// is covered by a full chunk of compute. np-exact pairwise preserved
// (identical mapping to r8: packed accum a0=(2g)&3 holds np accums
// {2a0,2a0+1}; fold == ((r0+r1)+(r2+r3))+((r4+r5)+(r6+r7)); fd=(B0+B1)+(B2+B3)).
// NO launch_bounds min-waves (r10: forced cap -> spill -> 4.4GB scratch traffic).
// ---------------------------------------------------------------------------
__global__ __launch_bounds__(256) void dist_kernel(
    const float* __restrict__ X, const float* __restrict__ C,
    const float* __restrict__ L, const float* __restrict__ G,
    const float2* __restrict__ RS, const int* __restrict__ T,
    unsigned long long* __restrict__ amin, float* __restrict__ partials)
{
    #pragma clang fp contract(off)
    __shared__ float cs[2][32][36];
    __shared__ float xls[2][32][36];
    __shared__ float red[256];
    __shared__ unsigned long long am[32][16];

    const int tid = threadIdx.x;
    const int tx = tid & 15, ty = tid >> 4;      // tx: k-slot, ty: b-pair
    const int k0 = blockIdx.x * 32, b0 = blockIdx.y * 32;
    const int r = tid >> 3;                       // 0..31 row to stage
    const int q = (tid & 7) * 4;                  // 0..28 d-offset in chunk

    const float* cg = C + (size_t)(k0 + r) * DD + q;
    const float* xg = X + (size_t)(b0 + r) * DD + q;

    const f32x2 zero2 = {0.f, 0.f};
    float l1[2][2] = {{0.f, 0.f}, {0.f, 0.f}};    // [k-slot][b]
    f32x2 rc[2][2][4];                            // [k][b][packed np accum]
    float s01[2][2], s23[2][2];
    #pragma unroll
    for (int kk = 0; kk < 2; ++kk)
        #pragma unroll
        for (int bb = 0; bb < 2; ++bb) {
            s01[kk][bb] = 0.f; s23[kk][bb] = 0.f;
            #pragma unroll
            for (int a = 0; a < 4; ++a) rc[kk][bb][a] = zero2;
        }

    f32x4 cv = *(const f32x4*)cg;                 // chunk 0 stages
    f32x4 xv = *(const f32x4*)xg;

    #pragma unroll 1
    for (int t = 0; t < 16; ++t) {
        const int buf = t & 1;
        *(f32x4*)&cs[buf][r][q] = cv;
        *(f32x4*)&xls[buf][r][q] = xv;
        if (t < 15) {                             // reg-only prefetch: barrier-safe
            cv = *(const f32x4*)(cg + (t + 1) * 32);
            xv = *(const f32x4*)(xg + (t + 1) * 32);
        }
        __syncthreads();

        #pragma unroll
        for (int g = 0; g < 8; ++g) {
            const f32x4 cA = *(const f32x4*)&cs[buf][tx][4 * g];
            const f32x4 cB = *(const f32x4*)&cs[buf][tx + 16][4 * g];
            const f32x4 xA = *(const f32x4*)&xls[buf][2 * ty][4 * g];
            const f32x4 xB = *(const f32x4*)&xls[buf][2 * ty + 1][4 * g];
            const int a0 = (2 * g) & 3;           // compile-time after unroll
            const int a1 = a0 + 1;
            f32x2 d;
            // combo [k0][b0]
            d = pk_sub(vlo(cA), vlo(xA));
            rc[0][0][a0] = pk_sq_acc(d, rc[0][0][a0]);
            l1[0][0] += fabsf(d.x); l1[0][0] += fabsf(d.y);
            d = pk_sub(vhi(cA), vhi(xA));
            rc[0][0][a1] = pk_sq_acc(d, rc[0][0][a1]);
            l1[0][0] += fabsf(d.x); l1[0][0] += fabsf(d.y);
            // combo [k0][b1]
            d = pk_sub(vlo(cA), vlo(xB));
            rc[0][1][a0] = pk_sq_acc(d, rc[0][1][a0]);
            l1[0][1] += fabsf(d.x); l1[0][1] += fabsf(d.y);
            d = pk_sub(vhi(cA), vhi(xB));
            rc[0][1][a1] = pk_sq_acc(d, rc[0][1][a1]);
            l1[0][1] += fabsf(d.x); l1[0][1] += fabsf(d.y);
            // combo [k1][b0]
            d = pk_sub(vlo(cB), vlo(xA));
            rc[1][0][a0] = pk_sq_acc(d, rc[1][0][a0]);
            l1[1][0] += fabsf(d.x); l1[1][0] += fabsf(d.y);
            d = pk_sub(vhi(cB), vhi(xA));
            rc[1][0][a1] = pk_sq_acc(d, rc[1][0][a1]);
            l1[1][0] += fabsf(d.x); l1[1][0] += fabsf(d.y);
            // combo [k1][b1]
            d = pk_sub(vlo(cB), vlo(xB));
            rc[1][1][a0] = pk_sq_acc(d, rc[1][1][a0]);
            l1[1][1] += fabsf(d.x); l1[1][1] += fabsf(d.y);
            d = pk_sub(vhi(cB), vhi(xB));
            rc[1][1][a1] = pk_sq_acc(d, rc[1][1][a1]);
            l1[1][1] += fabsf(d.x); l1[1][1] += fabsf(d.y);
        }

        if ((t & 3) == 3) {               // end of a 128-element block
            const int blk = t >> 2;       // 0..3
            #pragma unroll
            for (int kk = 0; kk < 2; ++kk)
                #pragma unroll
                for (int bb = 0; bb < 2; ++bb) {
                    // == ((r0+r1)+(r2+r3)) + ((r4+r5)+(r6+r7)) bit-exactly
                    const float b01 = (rc[kk][bb][0].x + rc[kk][bb][0].y)
                                    + (rc[kk][bb][1].x + rc[kk][bb][1].y);
                    const float b23 = (rc[kk][bb][2].x + rc[kk][bb][2].y)
                                    + (rc[kk][bb][3].x + rc[kk][bb][3].y);
                    const float bsum = b01 + b23;
                    if (blk == 0)      s01[kk][bb] = bsum;
                    else if (blk == 1) s01[kk][bb] = s01[kk][bb] + bsum;
                    else if (blk == 2) s23[kk][bb] = bsum;
                    else               s23[kk][bb] = s23[kk][bb] + bsum;
                    #pragma unroll
                    for (int a = 0; a < 4; ++a) rc[kk][bb][a] = zero2;
                }
        }
    }

    // ---- z recompute + delta partial + per-thread argmin pack ----
    const float invt = dev_invtemp(*T);
    float zp = 0.f;
    #pragma unroll
    for (int i = 0; i < 2; ++i) {
        const int b = b0 + 2 * ty + i;
        const float2 rs = RS[b];
        const int ka = k0 + tx;          // k-slot 0
        const int kb = k0 + tx + 16;     // k-slot 1
        const float fd0 = s01[0][i] + s23[0][i];   // ((B0+B1)+(B2+B3))
        const float fd1 = s01[1][i] + s23[1][i];
        const float z0 = expf((L[(size_t)b * KK + ka] + G[(size_t)b * KK + ka]) * invt - rs.x) * rs.y;
        const float z1 = expf((L[(size_t)b * KK + kb] + G[(size_t)b * KK + kb]) * invt - rs.x) * rs.y;
        zp += l1[0][i] * z0 + l1[1][i] * z1;
        const unsigned long long p0 =
            ((unsigned long long)__float_as_uint(fd0) << 32) | (unsigned long long)ka;
        const unsigned long long p1 =
            ((unsigned long long)__float_as_uint(fd1) << 32) | (unsigned long long)kb;
        am[2 * ty + i][tx] = p0 < p1 ? p0 : p1;
    }

    red[tid] = zp;
    __syncthreads();
    for (int st = 128; st > 0; st >>= 1) {
        if (tid < st) red[tid] += red[tid + st];
        __syncthreads();
    }
    if (tid == 0) partials[blockIdx.y * 32 + blockIdx.x] = red[0];

    if (tid < 32) {
        unsigned long long mv = am[tid][0];
        #pragma unroll
        for (int c = 1; c < 16; ++c) {
            unsigned long long v = am[tid][c];
            mv = v < mv ? v : mv;
        }
        atomicMin(&amin[b0 + tid], mv);
    }
}

// ---------------------------------------------------------------------------
// Kernel 3: finalize.
// ---------------------------------------------------------------------------
__global__ __launch_bounds__(1024) void finalize_kernel(
    const unsigned long long* __restrict__ amin,
    const float* __restrict__ partials, float* __restrict__ out)
{
    const int t = threadIdx.x;
    __shared__ float red[1024];
    const unsigned int idx = (unsigned int)(amin[t] & 0xFFFFFFFFULL);
    out[1048576 + t] = (float)idx;
    red[t] = partials[t];
    __syncthreads();
    for (int st = 512; st > 0; st >>= 1) {
        if (t < st) red[t] += red[t + st];
        __syncthreads();
    }
    if (t == 0)
        out[1049600] = red[0] * (1.0f / 536870912.0f); // /(B*K*D)
}

extern "C" void kernel_launch(void* const* d_in, const int* in_sizes, int n_in,
                              void* d_out, int out_size, void* d_ws, size_t ws_size,
                              hipStream_t stream) {
    const float* X  = (const float*)d_in[0];
    const float* C  = (const float*)d_in[1];
    const float* W1 = (const float*)d_in[2];
    const float* B1 = (const float*)d_in[3];
    const float* W2 = (const float*)d_in[4];
    const float* B2 = (const float*)d_in[5];
    const float* G  = (const float*)d_in[6];
    const int*   T  = (const int*)d_in[7];
    float* out = (float*)d_out;

    char* ws = (char*)d_ws;
    unsigned long long* amin = (unsigned long long*)ws;          // 8 KB
    float* partials = (float*)(ws + 8192);                       // 4 KB
    float2* rowstats = (float2*)(ws + 12288);                    // 8 KB

    mlp_softmax_kernel<<<BB, 256, 0, stream>>>(X, W1, B1, W2, B2, G, T, out, rowstats, amin);
    dist_kernel<<<dim3(32, 32), 256, 0, stream>>>(X, C, out, G, rowstats, T, amin, partials);
    finalize_kernel<<<1, 1024, 0, stream>>>(amin, partials, out);
}